// Round 4
// baseline (1237.882 us; speedup 1.0000x reference)
//
#include <hip/hip_runtime.h>
#include <hip/hip_fp16.h>

typedef _Float16 h8 __attribute__((ext_vector_type(8)));
typedef _Float16 h4 __attribute__((ext_vector_type(4)));
typedef _Float16 h2 __attribute__((ext_vector_type(2)));
typedef float f4 __attribute__((ext_vector_type(4)));

#define EMB    300
#define HID    200
#define NR     600     // 3*HID
#define KP     320     // K padded for MFMA (300 -> 10*32)
#define NPAD   1216    // N padded (2*600 -> 76*16)
#define SEQ    512
#define MTOT   16384   // B*S

#if defined(__has_builtin)
#if __has_builtin(__builtin_amdgcn_fdot2)
#define USE_FDOT2 1
#endif
#endif

__device__ __forceinline__ float fdot2f(h2 a, h2 b, float c) {
#ifdef USE_FDOT2
  return __builtin_amdgcn_fdot2(a, b, c, false);
#else
  return c + (float)a[0] * (float)b[0] + (float)a[1] * (float)b[1];
#endif
}

__device__ __forceinline__ float sigm(float x) { return 1.0f / (1.0f + __expf(-x)); }
__device__ __forceinline__ float tanhf_(float x) { return 1.0f - 2.0f / (1.0f + __expf(2.0f * x)); }

// ---------------- prep: convert/pad weights & biases ------------------------
// Wcvt:  input-proj weights, f16, [NPAD][KP]
// Whh2:  recurrent weights, k-major packed pairs: [2][100][600] h2
__global__ __launch_bounds__(256) void prep_kernel(
    const float* __restrict__ w_ih_f, const float* __restrict__ w_ih_b,
    const float* __restrict__ b_ih_f, const float* __restrict__ b_ih_b,
    const float* __restrict__ w_hh_f, const float* __restrict__ w_hh_b,
    _Float16* __restrict__ Wcvt, float* __restrict__ bias_cat,
    h2* __restrict__ Whh2) {
  int idx = blockIdx.x * 256 + threadIdx.x;
  if (idx < NPAD * KP) {
    int n = idx / KP, k = idx - n * KP;
    float v = 0.0f;
    if (k < EMB) {
      if (n < NR) v = w_ih_f[n * EMB + k];
      else if (n < 2 * NR) v = w_ih_b[(n - NR) * EMB + k];
    }
    Wcvt[idx] = (_Float16)v;
  }
  if (idx < NPAD) {
    float bv = 0.0f;
    if (idx < NR) bv = b_ih_f[idx];
    else if (idx < 2 * NR) bv = b_ih_b[idx - NR];
    bias_cat[idx] = bv;
  }
  if (idx < 2 * 100 * NR) {
    int d = idx / (100 * NR);
    int rem = idx - d * (100 * NR);
    int kk = rem / NR, r = rem - kk * NR;
    const float* w = d ? w_hh_b : w_hh_f;
    float w0 = w[r * HID + 2 * kk];
    float w1 = w[r * HID + 2 * kk + 1];
    Whh2[idx] = (h2){ (_Float16)w0, (_Float16)w1 };
  }
}

// ---------------- gi GEMM: gather + [16384,320]x[320,1216] f16 MFMA ---------
__global__ __launch_bounds__(512) void gi_gemm(
    const int* __restrict__ text, const float* __restrict__ emb,
    const _Float16* __restrict__ Wcvt, const float* __restrict__ bias_cat,
    __half* __restrict__ gi) {
  __shared__ _Float16 At[128][328];   // +8 halfs pad to break bank conflicts
  const int t = threadIdx.x;
  const int m0 = blockIdx.x * 128;
  {
    const int row = t >> 2;
    const int q = t & 3;
    const int tokid = text[m0 + row];
    const float4* ep = (const float4*)(emb + (size_t)tokid * EMB);
    for (int c4 = q; c4 < 75; c4 += 4) {
      float4 v = ep[c4];
      h4 hv = { (_Float16)v.x, (_Float16)v.y, (_Float16)v.z, (_Float16)v.w };
      *(h4*)&At[row][c4 * 4] = hv;
    }
    for (int c = 300 + q; c < 328; c += 4) At[row][c] = (_Float16)0.0f;
  }
  __syncthreads();

  const int wv = t >> 6, lane = t & 63;
  const int l15 = lane & 15, l4 = lane >> 4;
  const int nhalf = wv >> 2;
  const int ms0 = (wv & 3) * 2;
  const int r0 = ms0 * 16 + l15;
  const int r1 = r0 + 16;

  for (int c2 = 0; c2 < 2; ++c2) {
    const int nbase = nhalf * 38 + c2 * 19;
    f4 acc0[19], acc1[19];
#pragma unroll
    for (int i = 0; i < 19; ++i) { acc0[i] = (f4){0,0,0,0}; acc1[i] = (f4){0,0,0,0}; }
    for (int ks = 0; ks < 10; ++ks) {
      h8 a0 = *(const h8*)&At[r0][ks * 32 + l4 * 8];
      h8 a1 = *(const h8*)&At[r1][ks * 32 + l4 * 8];
#pragma unroll
      for (int i = 0; i < 19; ++i) {
        const h8* bp = (const h8*)(Wcvt + (size_t)((nbase + i) * 16 + l15) * KP + ks * 32 + l4 * 8);
        h8 bf = *bp;
        acc0[i] = __builtin_amdgcn_mfma_f32_16x16x32_f16(a0, bf, acc0[i], 0, 0, 0);
        acc1[i] = __builtin_amdgcn_mfma_f32_16x16x32_f16(a1, bf, acc1[i], 0, 0, 0);
      }
    }
#pragma unroll
    for (int i = 0; i < 19; ++i) {
      const int n = (nbase + i) * 16 + l15;
      const float bv = bias_cat[n];
#pragma unroll
      for (int j = 0; j < 4; ++j) {
        const int mA = m0 + ms0 * 16 + l4 * 4 + j;
        gi[(size_t)mA * NPAD + n] = (__half)(acc0[i][j] + bv);
        gi[(size_t)(mA + 16) * NPAD + n] = (__half)(acc1[i][j] + bv);
      }
    }
  }
}

// ---------------- GRU recurrence: 64 WGs = (dir, batch) ---------------------
// 256 threads, 1 wave/SIMD. Thread u<200 owns hidden unit u and its THREE
// gate rows (r,z,n) entirely in VGPRs (300 packed-f16 pairs). No shuffles,
// no y roundtrip, ONE barrier per step (h_pad double-buffered).
__global__ __launch_bounds__(256, 1) void gru_rec(
    const h2* __restrict__ Whh2,
    const float* __restrict__ b_hh_f, const float* __restrict__ b_hh_b,
    const float* __restrict__ h0_f,  const float* __restrict__ h0_b,
    const __half* __restrict__ gi, __half* __restrict__ hs) {
  const int t = threadIdx.x;
  const int dir = blockIdx.x >> 5;
  const int b = blockIdx.x & 31;
  const float* bhh_g = dir ? b_hh_b : b_hh_f;
  const float* h0 = dir ? h0_b : h0_f;

  __shared__ __align__(16) _Float16 h_pad[2][208];   // double-buffered h (f16)
  __shared__ __align__(16) _Float16 gi_lds[2][608];  // double-buffered gi row

  const int u = t;
  const bool act = (u < HID);
  const int us = act ? u : 0;

  // ---- one-time: load this unit's 3 weight rows, k-major coalesced ----
  h2 w0[100], w1[100], w2[100];
  const h2* Wd = Whh2 + (size_t)dir * 100 * NR;
#pragma unroll
  for (int kk = 0; kk < 100; ++kk) {
    w0[kk] = Wd[kk * NR + us];
    w1[kk] = Wd[kk * NR + 200 + us];
    w2[kk] = Wd[kk * NR + 400 + us];
  }
  float b0 = 0, b1 = 0, b2 = 0, hreg = 0;
  if (act) {
    b0 = bhh_g[u]; b1 = bhh_g[200 + u]; b2 = bhh_g[400 + u];
    hreg = (h0[b * HID + u] - 0.5f) * (1.0f / (float)HID);
    h_pad[0][u] = (_Float16)hreg;
  }
  {
    const int s0 = dir ? (SEQ - 1) : 0;
    const h4* g0 = (const h4*)(gi + (size_t)(b * SEQ + s0) * NPAD + dir * NR);
    if (t < 150) ((h4*)gi_lds[0])[t] = g0[t];
  }
  __syncthreads();

  for (int st = 0; st < SEQ; ++st) {
    const int cur = st & 1, nxt = cur ^ 1;
    const int s = dir ? (SEQ - 1 - st) : st;
    // 1. prefetch next step's gi row (lands after gates, read next step)
    h4 pf = (h4){(_Float16)0, (_Float16)0, (_Float16)0, (_Float16)0};
    const bool do_pf = (t < 150) && (st < SEQ - 1);
    if (do_pf) {
      const int sn = dir ? (SEQ - 2 - st) : (st + 1);
      pf = ((const h4*)(gi + (size_t)(b * SEQ + sn) * NPAD + dir * NR))[t];
    }
    // 2. GEMV for 3 gate rows; h read as b128 broadcast; 6 accum chains
    float a0a = 0, a0b = 0, a1a = 0, a1b = 0, a2a = 0, a2b = 0;
#pragma unroll
    for (int c = 0; c < 25; ++c) {
      h8 hv = *(const h8*)&h_pad[cur][c * 8];
      h2 p0 = {hv[0], hv[1]}, p1 = {hv[2], hv[3]};
      h2 p2 = {hv[4], hv[5]}, p3 = {hv[6], hv[7]};
      a0a = fdot2f(w0[c * 4 + 0], p0, a0a); a0b = fdot2f(w0[c * 4 + 1], p1, a0b);
      a0a = fdot2f(w0[c * 4 + 2], p2, a0a); a0b = fdot2f(w0[c * 4 + 3], p3, a0b);
      a1a = fdot2f(w1[c * 4 + 0], p0, a1a); a1b = fdot2f(w1[c * 4 + 1], p1, a1b);
      a1a = fdot2f(w1[c * 4 + 2], p2, a1a); a1b = fdot2f(w1[c * 4 + 3], p3, a1b);
      a2a = fdot2f(w2[c * 4 + 0], p0, a2a); a2b = fdot2f(w2[c * 4 + 1], p1, a2b);
      a2a = fdot2f(w2[c * 4 + 2], p2, a2a); a2b = fdot2f(w2[c * 4 + 3], p3, a2b);
    }
    // 3. gates in-register (PyTorch GRUCell order r,z,n)
    if (act) {
      const float yr = a0a + a0b + b0;
      const float yz = a1a + a1b + b1;
      const float yn = a2a + a2b + b2;
      const float ir = (float)gi_lds[cur][u];
      const float iz = (float)gi_lds[cur][200 + u];
      const float inn = (float)gi_lds[cur][400 + u];
      const float r = sigm(ir + yr);
      const float z = sigm(iz + yz);
      const float n = tanhf_(inn + r * yn);
      hreg = (1.0f - z) * n + z * hreg;
      h_pad[nxt][u] = (_Float16)hreg;
      hs[(size_t)(b * SEQ + s) * 400 + dir * HID + u] = (__half)hreg;
    }
    // 4. land prefetched gi row
    if (do_pf) ((h4*)gi_lds[nxt])[t] = pf;
    __syncthreads();
  }
}

// ---------------- final linear: [16384,400] x [400,10] ---------------------
__global__ __launch_bounds__(256) void final_linear(
    const __half* __restrict__ hs, const float* __restrict__ lin_w,
    const float* __restrict__ lin_b, float* __restrict__ out) {
  __shared__ _Float16 hsl[64][400];
  __shared__ _Float16 lwl[10][400];
  const int t = threadIdx.x;
  const int m0 = blockIdx.x * 64;
  const ushort4* hp = (const ushort4*)(hs + (size_t)m0 * 400);
  for (int idx = t; idx < 64 * 100; idx += 256) {
    ushort4 v = hp[idx];
    const int row = idx / 100, c = idx - row * 100;
    *(ushort4*)&hsl[row][c * 4] = v;
  }
  for (int idx = t; idx < 10 * 400; idx += 256) {
    (&lwl[0][0])[idx] = (_Float16)lin_w[idx];
  }
  __syncthreads();
  for (int idx = t; idx < 640; idx += 256) {
    const int m = idx / 10, c = idx - (idx / 10) * 10;
    const h2* hr = (const h2*)hsl[m];
    const h2* wr = (const h2*)lwl[c];
    float acc = 0.0f;
#pragma unroll 8
    for (int kk = 0; kk < 200; ++kk) acc = fdot2f(hr[kk], wr[kk], acc);
    out[(size_t)(m0 + m) * 10 + c] = acc + lin_b[c];
  }
}

extern "C" void kernel_launch(void* const* d_in, const int* in_sizes, int n_in,
                              void* d_out, int out_size, void* d_ws, size_t ws_size,
                              hipStream_t stream) {
  const int*   text   = (const int*)d_in[0];
  const float* emb    = (const float*)d_in[1];
  const float* w_ih_f = (const float*)d_in[2];
  const float* w_hh_f = (const float*)d_in[3];
  const float* b_ih_f = (const float*)d_in[4];
  const float* b_hh_f = (const float*)d_in[5];
  const float* w_ih_b = (const float*)d_in[6];
  const float* w_hh_b = (const float*)d_in[7];
  const float* b_ih_b = (const float*)d_in[8];
  const float* b_hh_b = (const float*)d_in[9];
  const float* lin_w  = (const float*)d_in[10];
  const float* lin_b  = (const float*)d_in[11];
  const float* h0_f   = (const float*)d_in[12];
  const float* h0_b   = (const float*)d_in[13];
  float* out = (float*)d_out;

  char* ws = (char*)d_ws;
  _Float16* Wcvt     = (_Float16*)(ws);                 //   778,240 B
  float*    bias_cat = (float*)(ws + 778240);           //     4,864 B
  __half*   gi       = (__half*)(ws + 783360);          // 39,845,888 B
  __half*   hs       = (__half*)(ws + 40629248);        // 13,107,200 B
  h2*       Whh2     = (h2*)(ws + 53736448);            //   480,000 B (end ~54.2MB)

  prep_kernel<<<dim3((NPAD * KP + 255) / 256), dim3(256), 0, stream>>>(
      w_ih_f, w_ih_b, b_ih_f, b_ih_b, w_hh_f, w_hh_b, Wcvt, bias_cat, Whh2);
  gi_gemm<<<dim3(MTOT / 128), dim3(512), 0, stream>>>(
      text, emb, Wcvt, bias_cat, gi);
  gru_rec<<<dim3(64), dim3(256), 0, stream>>>(
      Whh2, b_hh_f, b_hh_b, h0_f, h0_b, gi, hs);
  final_linear<<<dim3(MTOT / 64), dim3(256), 0, stream>>>(
      hs, lin_w, lin_b, out);
}

// Round 5
// 883.296 us; speedup vs baseline: 1.4014x; 1.4014x over previous
//
#include <hip/hip_runtime.h>
#include <hip/hip_fp16.h>

typedef _Float16 h8 __attribute__((ext_vector_type(8)));
typedef _Float16 h4 __attribute__((ext_vector_type(4)));
typedef _Float16 h2 __attribute__((ext_vector_type(2)));
typedef float f4 __attribute__((ext_vector_type(4)));

#define EMB    300
#define HID    200
#define NR     600     // 3*HID
#define KP     320     // K padded for MFMA (300 -> 10*32)
#define NPAD   1216    // N padded (2*600 -> 76*16)
#define SEQ    512
#define MTOT   16384   // B*S

#if defined(__has_builtin)
#if __has_builtin(__builtin_amdgcn_fdot2)
#define USE_FDOT2 1
#endif
#endif

__device__ __forceinline__ float fdot2f(h2 a, h2 b, float c) {
#ifdef USE_FDOT2
  return __builtin_amdgcn_fdot2(a, b, c, false);
#else
  return c + (float)a[0] * (float)b[0] + (float)a[1] * (float)b[1];
#endif
}

__device__ __forceinline__ float sigm(float x) { return 1.0f / (1.0f + __expf(-x)); }
__device__ __forceinline__ float tanhf_(float x) { return 1.0f - 2.0f / (1.0f + __expf(2.0f * x)); }

// ---------------- prep: convert/pad weights & biases ------------------------
// Wcvt:  input-proj weights, f16, [NPAD][KP]
// Whh2:  recurrent weights, k-major packed pairs: [2][100][600] h2
__global__ __launch_bounds__(256) void prep_kernel(
    const float* __restrict__ w_ih_f, const float* __restrict__ w_ih_b,
    const float* __restrict__ b_ih_f, const float* __restrict__ b_ih_b,
    const float* __restrict__ w_hh_f, const float* __restrict__ w_hh_b,
    _Float16* __restrict__ Wcvt, float* __restrict__ bias_cat,
    h2* __restrict__ Whh2) {
  int idx = blockIdx.x * 256 + threadIdx.x;
  if (idx < NPAD * KP) {
    int n = idx / KP, k = idx - n * KP;
    float v = 0.0f;
    if (k < EMB) {
      if (n < NR) v = w_ih_f[n * EMB + k];
      else if (n < 2 * NR) v = w_ih_b[(n - NR) * EMB + k];
    }
    Wcvt[idx] = (_Float16)v;
  }
  if (idx < NPAD) {
    float bv = 0.0f;
    if (idx < NR) bv = b_ih_f[idx];
    else if (idx < 2 * NR) bv = b_ih_b[idx - NR];
    bias_cat[idx] = bv;
  }
  if (idx < 2 * 100 * NR) {
    int d = idx / (100 * NR);
    int rem = idx - d * (100 * NR);
    int kk = rem / NR, r = rem - kk * NR;
    const float* w = d ? w_hh_b : w_hh_f;
    float w0 = w[r * HID + 2 * kk];
    float w1 = w[r * HID + 2 * kk + 1];
    Whh2[idx] = (h2){ (_Float16)w0, (_Float16)w1 };
  }
}

// ---------------- gi GEMM: gather + [16384,320]x[320,1216] f16 MFMA ---------
__global__ __launch_bounds__(512) void gi_gemm(
    const int* __restrict__ text, const float* __restrict__ emb,
    const _Float16* __restrict__ Wcvt, const float* __restrict__ bias_cat,
    __half* __restrict__ gi) {
  __shared__ _Float16 At[128][328];   // +8 halfs pad to break bank conflicts
  const int t = threadIdx.x;
  const int m0 = blockIdx.x * 128;
  {
    const int row = t >> 2;
    const int q = t & 3;
    const int tokid = text[m0 + row];
    const float4* ep = (const float4*)(emb + (size_t)tokid * EMB);
    for (int c4 = q; c4 < 75; c4 += 4) {
      float4 v = ep[c4];
      h4 hv = { (_Float16)v.x, (_Float16)v.y, (_Float16)v.z, (_Float16)v.w };
      *(h4*)&At[row][c4 * 4] = hv;
    }
    for (int c = 300 + q; c < 328; c += 4) At[row][c] = (_Float16)0.0f;
  }
  __syncthreads();

  const int wv = t >> 6, lane = t & 63;
  const int l15 = lane & 15, l4 = lane >> 4;
  const int nhalf = wv >> 2;
  const int ms0 = (wv & 3) * 2;
  const int r0 = ms0 * 16 + l15;
  const int r1 = r0 + 16;

  for (int c2 = 0; c2 < 2; ++c2) {
    const int nbase = nhalf * 38 + c2 * 19;
    f4 acc0[19], acc1[19];
#pragma unroll
    for (int i = 0; i < 19; ++i) { acc0[i] = (f4){0,0,0,0}; acc1[i] = (f4){0,0,0,0}; }
    for (int ks = 0; ks < 10; ++ks) {
      h8 a0 = *(const h8*)&At[r0][ks * 32 + l4 * 8];
      h8 a1 = *(const h8*)&At[r1][ks * 32 + l4 * 8];
#pragma unroll
      for (int i = 0; i < 19; ++i) {
        const h8* bp = (const h8*)(Wcvt + (size_t)((nbase + i) * 16 + l15) * KP + ks * 32 + l4 * 8);
        h8 bf = *bp;
        acc0[i] = __builtin_amdgcn_mfma_f32_16x16x32_f16(a0, bf, acc0[i], 0, 0, 0);
        acc1[i] = __builtin_amdgcn_mfma_f32_16x16x32_f16(a1, bf, acc1[i], 0, 0, 0);
      }
    }
#pragma unroll
    for (int i = 0; i < 19; ++i) {
      const int n = (nbase + i) * 16 + l15;
      const float bv = bias_cat[n];
#pragma unroll
      for (int j = 0; j < 4; ++j) {
        const int mA = m0 + ms0 * 16 + l4 * 4 + j;
        gi[(size_t)mA * NPAD + n] = (__half)(acc0[i][j] + bv);
        gi[(size_t)(mA + 16) * NPAD + n] = (__half)(acc1[i][j] + bv);
      }
    }
  }
}

// ---------------- GRU recurrence: 64 WGs = (dir, batch) ---------------------
// 640 threads (10 waves). Thread r<600 owns ONE gate row (K=200 in 100 h2
// VGPRs — small enough to promote; round-4's 300 h2/thread spilled to
// scratch, VGPR_Count=184 < 300 proved it). Per step: uniform b128 h
// broadcasts -> 100 dot2 (4 chains, bias folded into acc) -> y_lds[r]
// (conflict-free) -> barrier -> 200 threads do gates in-register -> barrier.
__global__ __launch_bounds__(640, 2) void gru_rec(
    const h2* __restrict__ Whh2,
    const float* __restrict__ b_hh_f, const float* __restrict__ b_hh_b,
    const float* __restrict__ h0_f,  const float* __restrict__ h0_b,
    const __half* __restrict__ gi, __half* __restrict__ hs) {
  const int t = threadIdx.x;
  const int dir = blockIdx.x >> 5;
  const int b = blockIdx.x & 31;
  const float* bhh_g = dir ? b_hh_b : b_hh_f;
  const float* h0 = dir ? h0_b : h0_f;

  __shared__ __align__(16) _Float16 h_sh[208];       // h state, f16 (b128-read)
  __shared__ float y_lds[NR];
  __shared__ __align__(16) _Float16 gi_lds[2][608];  // double-buffered gi row

  const int r = t;
  const bool arow = (r < NR);
  const int rr = arow ? r : 0;

  // ---- one-time: this row's 200 weights as 100 h2 VGPRs (coalesced) ----
  h2 w[100];
  const h2* Wd = Whh2 + (size_t)dir * 100 * NR;
#pragma unroll
  for (int kk = 0; kk < 100; ++kk) w[kk] = Wd[kk * NR + rr];
  const float ybias = arow ? bhh_g[r] : 0.0f;

  float hreg = 0.0f;
  if (t < HID) {
    hreg = (h0[b * HID + t] - 0.5f) * (1.0f / (float)HID);
    h_sh[t] = (_Float16)hreg;
  }
  {
    const int s0 = dir ? (SEQ - 1) : 0;
    const h4* g0 = (const h4*)(gi + (size_t)(b * SEQ + s0) * NPAD + dir * NR);
    if (t < 150) ((h4*)gi_lds[0])[t] = g0[t];
  }
  __syncthreads();

  for (int st = 0; st < SEQ; ++st) {
    const int cur = st & 1, nxt = cur ^ 1;
    const int s = dir ? (SEQ - 1 - st) : st;
    // 1. prefetch next step's gi row (lands in phase 4)
    h4 pf = (h4){(_Float16)0, (_Float16)0, (_Float16)0, (_Float16)0};
    const bool do_pf = (t < 150) && (st < SEQ - 1);
    if (do_pf) {
      const int sn = dir ? (SEQ - 2 - st) : (st + 1);
      pf = ((const h4*)(gi + (size_t)(b * SEQ + sn) * NPAD + dir * NR))[t];
    }
    // 2. GEMV: y[r] = W_hh[r,:] . h  (uniform b128 broadcasts, 4 chains)
    float a0 = ybias, a1 = 0.0f, a2 = 0.0f, a3 = 0.0f;
#pragma unroll
    for (int j = 0; j < 25; ++j) {
      h8 hv = *(const h8*)&h_sh[j * 8];
      a0 = fdot2f(w[4 * j + 0], (h2){hv[0], hv[1]}, a0);
      a1 = fdot2f(w[4 * j + 1], (h2){hv[2], hv[3]}, a1);
      a2 = fdot2f(w[4 * j + 2], (h2){hv[4], hv[5]}, a2);
      a3 = fdot2f(w[4 * j + 3], (h2){hv[6], hv[7]}, a3);
    }
    if (arow) y_lds[r] = (a0 + a1) + (a2 + a3);
    __syncthreads();
    // 3. gates + state update (PyTorch GRUCell order r,z,n)
    if (t < HID) {
      const _Float16* gih = gi_lds[cur];
      const float ir = (float)gih[t];
      const float iz = (float)gih[200 + t];
      const float inn = (float)gih[400 + t];
      const float rg = sigm(ir + y_lds[t]);
      const float zg = sigm(iz + y_lds[200 + t]);
      const float ng = tanhf_(inn + rg * y_lds[400 + t]);
      hreg = (1.0f - zg) * ng + zg * hreg;
      h_sh[t] = (_Float16)hreg;
      hs[(size_t)(b * SEQ + s) * 400 + dir * HID + t] = (__half)hreg;
    }
    // 4. land prefetched gi row
    if (do_pf) ((h4*)gi_lds[nxt])[t] = pf;
    __syncthreads();
  }
}

// ---------------- final linear: [16384,400] x [400,10] ---------------------
__global__ __launch_bounds__(256) void final_linear(
    const __half* __restrict__ hs, const float* __restrict__ lin_w,
    const float* __restrict__ lin_b, float* __restrict__ out) {
  __shared__ _Float16 hsl[64][400];
  __shared__ _Float16 lwl[10][400];
  const int t = threadIdx.x;
  const int m0 = blockIdx.x * 64;
  const ushort4* hp = (const ushort4*)(hs + (size_t)m0 * 400);
  for (int idx = t; idx < 64 * 100; idx += 256) {
    ushort4 v = hp[idx];
    const int row = idx / 100, c = idx - row * 100;
    *(ushort4*)&hsl[row][c * 4] = v;
  }
  for (int idx = t; idx < 10 * 400; idx += 256) {
    (&lwl[0][0])[idx] = (_Float16)lin_w[idx];
  }
  __syncthreads();
  for (int idx = t; idx < 640; idx += 256) {
    const int m = idx / 10, c = idx - (idx / 10) * 10;
    const h2* hr = (const h2*)hsl[m];
    const h2* wr = (const h2*)lwl[c];
    float acc = 0.0f;
#pragma unroll 8
    for (int kk = 0; kk < 200; ++kk) acc = fdot2f(hr[kk], wr[kk], acc);
    out[(size_t)(m0 + m) * 10 + c] = acc + lin_b[c];
  }
}

extern "C" void kernel_launch(void* const* d_in, const int* in_sizes, int n_in,
                              void* d_out, int out_size, void* d_ws, size_t ws_size,
                              hipStream_t stream) {
  const int*   text   = (const int*)d_in[0];
  const float* emb    = (const float*)d_in[1];
  const float* w_ih_f = (const float*)d_in[2];
  const float* w_hh_f = (const float*)d_in[3];
  const float* b_ih_f = (const float*)d_in[4];
  const float* b_hh_f = (const float*)d_in[5];
  const float* w_ih_b = (const float*)d_in[6];
  const float* w_hh_b = (const float*)d_in[7];
  const float* b_ih_b = (const float*)d_in[8];
  const float* b_hh_b = (const float*)d_in[9];
  const float* lin_w  = (const float*)d_in[10];
  const float* lin_b  = (const float*)d_in[11];
  const float* h0_f   = (const float*)d_in[12];
  const float* h0_b   = (const float*)d_in[13];
  float* out = (float*)d_out;

  char* ws = (char*)d_ws;
  _Float16* Wcvt     = (_Float16*)(ws);                 //   778,240 B
  float*    bias_cat = (float*)(ws + 778240);           //     4,864 B
  __half*   gi       = (__half*)(ws + 783360);          // 39,845,888 B
  __half*   hs       = (__half*)(ws + 40629248);        // 13,107,200 B
  h2*       Whh2     = (h2*)(ws + 53736448);            //   480,000 B (end ~54.2MB)

  prep_kernel<<<dim3((NPAD * KP + 255) / 256), dim3(256), 0, stream>>>(
      w_ih_f, w_ih_b, b_ih_f, b_ih_b, w_hh_f, w_hh_b, Wcvt, bias_cat, Whh2);
  gi_gemm<<<dim3(MTOT / 128), dim3(512), 0, stream>>>(
      text, emb, Wcvt, bias_cat, gi);
  gru_rec<<<dim3(64), dim3(640), 0, stream>>>(
      Whh2, b_hh_f, b_hh_b, h0_f, h0_b, gi, hs);
  final_linear<<<dim3(MTOT / 64), dim3(256), 0, stream>>>(
      hs, lin_w, lin_b, out);
}

// Round 6
// 725.993 us; speedup vs baseline: 1.7051x; 1.2167x over previous
//
#include <hip/hip_runtime.h>
#include <hip/hip_fp16.h>

typedef _Float16 h8 __attribute__((ext_vector_type(8)));
typedef _Float16 h4 __attribute__((ext_vector_type(4)));
typedef _Float16 h2 __attribute__((ext_vector_type(2)));
typedef float f4 __attribute__((ext_vector_type(4)));

#define EMB    300
#define HID    200
#define NR     600       // 3*HID
#define GIS    1200      // gi row stride (halfs)
#define SEQ    512
#define MTOT   16384     // B*S
#define WROW_N 240000    // 2*600*200 halfs
#define WROW_P 240032    // + 32-half tail pad

#if defined(__has_builtin)
#if __has_builtin(__builtin_amdgcn_fdot2)
#define USE_FDOT2 1
#endif
#endif

__device__ __forceinline__ float fdot2f(h2 a, h2 b, float c) {
#ifdef USE_FDOT2
  return __builtin_amdgcn_fdot2(a, b, c, false);
#else
  return c + (float)a[0] * (float)b[0] + (float)a[1] * (float)b[1];
#endif
}

__device__ __forceinline__ float sigm(float x) { return 1.0f / (1.0f + __expf(-x)); }
__device__ __forceinline__ float tanhf_(float x) { return 1.0f - 2.0f / (1.0f + __expf(2.0f * x)); }

// quad butterfly sum via DPP (VALU-only; avoids the DS pipe entirely)
__device__ __forceinline__ float qsum(float x) {
  x += __int_as_float(__builtin_amdgcn_mov_dpp(__float_as_int(x), 0xB1, 0xF, 0xF, true)); // quad_perm [1,0,3,2]
  x += __int_as_float(__builtin_amdgcn_mov_dpp(__float_as_int(x), 0x4E, 0xF, 0xF, true)); // quad_perm [2,3,0,1]
  return x;
}

// ---------------- prep: all weight conversions -----------------------------
// Wfrag: input-proj weights in MFMA B-fragment order:
//        [(nt*10+ks)*64 + lane]*8 + e  <->  n = nt*16+(lane&15), k = ks*32+(lane>>4)*8+e
// Wrow:  recurrent weights row-major f16 [2][600][200] (+32-half zero tail)
__global__ __launch_bounds__(256) void prep_kernel(
    const float* __restrict__ w_ih_f, const float* __restrict__ w_ih_b,
    const float* __restrict__ b_ih_f, const float* __restrict__ b_ih_b,
    const float* __restrict__ w_hh_f, const float* __restrict__ w_hh_b,
    _Float16* __restrict__ Wfrag, float* __restrict__ bias_cat,
    _Float16* __restrict__ Wrow) {
  int idx = blockIdx.x * 256 + threadIdx.x;
  if (idx < 76 * 10 * 64 * 8) {
    int e = idx & 7, f = idx >> 3;
    int lane = f & 63; f >>= 6;
    int ks = f % 10, nt = f / 10;
    int n = nt * 16 + (lane & 15);
    int k = ks * 32 + (lane >> 4) * 8 + e;
    float v = 0.0f;
    if (k < EMB) {
      if (n < NR) v = w_ih_f[n * EMB + k];
      else if (n < 2 * NR) v = w_ih_b[(n - NR) * EMB + k];
    }
    Wfrag[idx] = (_Float16)v;
  }
  if (idx < 1216) {
    float bv = 0.0f;
    if (idx < NR) bv = b_ih_f[idx];
    else if (idx < 2 * NR) bv = b_ih_b[idx - NR];
    bias_cat[idx] = bv;
  }
  if (idx < WROW_P) {
    float v = 0.0f;
    if (idx < WROW_N) {
      int d = idx / 120000, rem = idx - d * 120000;
      v = (d ? w_hh_b : w_hh_f)[rem];
    }
    Wrow[idx] = (_Float16)v;
  }
}

// ---------------- gi GEMM: gather + [16384,320]x[320,1216] f16 MFMA ---------
__global__ __launch_bounds__(512) void gi_gemm(
    const int* __restrict__ text, const float* __restrict__ emb,
    const _Float16* __restrict__ Wfrag, const float* __restrict__ bias_cat,
    __half* __restrict__ gi) {
  __shared__ _Float16 At[128][328];   // +8 halfs pad to break bank conflicts
  const int t = threadIdx.x;
  const int m0 = blockIdx.x * 128;
  {
    const int row = t >> 2;
    const int q = t & 3;
    const int tokid = text[m0 + row];
    const float4* ep = (const float4*)(emb + (size_t)tokid * EMB);
    for (int c4 = q; c4 < 75; c4 += 4) {
      float4 v = ep[c4];
      h4 hv = { (_Float16)v.x, (_Float16)v.y, (_Float16)v.z, (_Float16)v.w };
      *(h4*)&At[row][c4 * 4] = hv;
    }
    for (int c = 300 + q; c < 328; c += 4) At[row][c] = (_Float16)0.0f;
  }
  __syncthreads();

  const int wv = t >> 6, lane = t & 63;
  const int l15 = lane & 15, l4 = lane >> 4;
  const int nhalf = wv >> 2;
  const int ms0 = (wv & 3) * 2;
  const int r0 = ms0 * 16 + l15;
  const int r1 = r0 + 16;

  for (int c2 = 0; c2 < 2; ++c2) {
    const int nbase = nhalf * 38 + c2 * 19;
    f4 acc0[19], acc1[19];
#pragma unroll
    for (int i = 0; i < 19; ++i) { acc0[i] = (f4){0,0,0,0}; acc1[i] = (f4){0,0,0,0}; }
    for (int ks = 0; ks < 10; ++ks) {
      h8 a0 = *(const h8*)&At[r0][ks * 32 + l4 * 8];
      h8 a1 = *(const h8*)&At[r1][ks * 32 + l4 * 8];
#pragma unroll
      for (int i = 0; i < 19; ++i) {
        // coalesced fragment load: lane-consecutive 16B
        h8 bf = ((const h8*)Wfrag)[((size_t)(nbase + i) * 10 + ks) * 64 + lane];
        acc0[i] = __builtin_amdgcn_mfma_f32_16x16x32_f16(a0, bf, acc0[i], 0, 0, 0);
        acc1[i] = __builtin_amdgcn_mfma_f32_16x16x32_f16(a1, bf, acc1[i], 0, 0, 0);
      }
    }
#pragma unroll
    for (int i = 0; i < 19; ++i) {
      const int n = (nbase + i) * 16 + l15;
      if (n < GIS) {
        const float bv = bias_cat[n];
#pragma unroll
        for (int j = 0; j < 4; ++j) {
          const int mA = m0 + ms0 * 16 + l4 * 4 + j;
          gi[(size_t)mA * GIS + n] = (__half)(acc0[i][j] + bv);
          gi[(size_t)(mA + 16) * GIS + n] = (__half)(acc1[i][j] + bv);
        }
      }
    }
  }
}

// ---------------- GRU recurrence: 64 WGs = (dir, batch) ---------------------
// 512 threads (8 waves, 2/SIMD). Thread (rg<120, kq<4) owns rows 5rg..5rg+4,
// K-slice [56kq, 56kq+56) as 35 NAMED h8 registers (SSA -> cannot be scratch;
// rounds 4/5 proved array allocas spill: VGPR 184/84 < needed). h padded to
// 224 with zeros so the kq=3 overhang contributes 0. Quad-lane reduce = DPP.
#define DOT8(w, x, A, B)                                        \
  A = fdot2f((h2){(w)[0],(w)[1]}, (h2){(x)[0],(x)[1]}, A);      \
  B = fdot2f((h2){(w)[2],(w)[3]}, (h2){(x)[2],(x)[3]}, B);      \
  A = fdot2f((h2){(w)[4],(w)[5]}, (h2){(x)[4],(x)[5]}, A);      \
  B = fdot2f((h2){(w)[6],(w)[7]}, (h2){(x)[6],(x)[7]}, B);

#define ROW_VARS(i) h8 w##i##0, w##i##1, w##i##2, w##i##3, w##i##4, w##i##5, w##i##6
#define ROW_LOAD(i) do { const h8* p = (const h8*)(Wrow + wbase + (size_t)(i) * 200); \
  w##i##0 = p[0]; w##i##1 = p[1]; w##i##2 = p[2]; w##i##3 = p[3];                     \
  w##i##4 = p[4]; w##i##5 = p[5]; w##i##6 = p[6]; } while (0)
#define ROW_DOT(i, A, B) do {                                   \
  DOT8(w##i##0, x0, A, B); DOT8(w##i##1, x1, A, B);             \
  DOT8(w##i##2, x2, A, B); DOT8(w##i##3, x3, A, B);             \
  DOT8(w##i##4, x4, A, B); DOT8(w##i##5, x5, A, B);             \
  DOT8(w##i##6, x6, A, B); } while (0)

__global__ __launch_bounds__(512, 1) void gru_rec(
    const _Float16* __restrict__ Wrow,
    const float* __restrict__ b_hh_f, const float* __restrict__ b_hh_b,
    const float* __restrict__ h0_f,  const float* __restrict__ h0_b,
    const __half* __restrict__ gi, __half* __restrict__ hs) {
  const int t = threadIdx.x;
  const int dir = blockIdx.x >> 5;
  const int b = blockIdx.x & 31;
  const float* bhh_g = dir ? b_hh_b : b_hh_f;
  const float* h0 = dir ? h0_b : h0_f;

  __shared__ __align__(16) _Float16 h_sh[224];       // h state f16, zero-padded tail
  __shared__ float y_lds[NR];
  __shared__ __align__(16) _Float16 gi_lds[2][608];  // double-buffered gi row

  const int rg = t >> 2, kq = t & 3;
  const bool arow = (rg < 120);
  const int rbase = arow ? rg * 5 : 0;
  const size_t wbase = (size_t)dir * 120000 + (size_t)rbase * 200 + 56 * kq;

  // ---- one-time: 35 named h8 weight registers (5 rows x 56 halfs) ----
  ROW_VARS(0); ROW_VARS(1); ROW_VARS(2); ROW_VARS(3); ROW_VARS(4);
  ROW_LOAD(0); ROW_LOAD(1); ROW_LOAD(2); ROW_LOAD(3); ROW_LOAD(4);

  float bb0 = 0, bb1 = 0, bb2 = 0, hreg = 0;
  if (t < HID) {
    bb0 = bhh_g[t]; bb1 = bhh_g[200 + t]; bb2 = bhh_g[400 + t];
    hreg = (h0[b * HID + t] - 0.5f) * (1.0f / (float)HID);
  }
  if (t < 224) h_sh[t] = (t < HID) ? (_Float16)hreg : (_Float16)0.0f;
  {
    const int s0 = dir ? (SEQ - 1) : 0;
    const h4* g0 = (const h4*)(gi + (size_t)(b * SEQ + s0) * GIS + dir * NR);
    if (t < 150) ((h4*)gi_lds[0])[t] = g0[t];
  }
  __syncthreads();

  const h8* hh = (const h8*)&h_sh[56 * kq];

  for (int st = 0; st < SEQ; ++st) {
    const int cur = st & 1, nxt = cur ^ 1;
    const int s = dir ? (SEQ - 1 - st) : st;
    // 1. prefetch next step's gi row (lands in phase 4)
    h4 pf = (h4){(_Float16)0, (_Float16)0, (_Float16)0, (_Float16)0};
    const bool do_pf = (t < 150) && (st < SEQ - 1);
    if (do_pf) {
      const int sn = dir ? (SEQ - 2 - st) : (st + 1);
      pf = ((const h4*)(gi + (size_t)(b * SEQ + sn) * GIS + dir * NR))[t];
    }
    // 2. GEMV partials: 5 rows x 28 dot2 on the thread's K-slice
    h8 x0 = hh[0], x1 = hh[1], x2 = hh[2], x3 = hh[3], x4 = hh[4], x5 = hh[5], x6 = hh[6];
    float a0A = 0, a0B = 0, a1A = 0, a1B = 0, a2A = 0, a2B = 0,
          a3A = 0, a3B = 0, a4A = 0, a4B = 0;
    ROW_DOT(0, a0A, a0B); ROW_DOT(1, a1A, a1B); ROW_DOT(2, a2A, a2B);
    ROW_DOT(3, a3A, a3B); ROW_DOT(4, a4A, a4B);
    // 3. quad reduce (DPP, VALU-only) + y write (conflict-free)
    const float s0 = qsum(a0A + a0B), s1 = qsum(a1A + a1B), s2 = qsum(a2A + a2B),
                s3 = qsum(a3A + a3B), s4 = qsum(a4A + a4B);
    if (arow) {
      y_lds[rbase + kq] = (kq == 0) ? s0 : (kq == 1) ? s1 : (kq == 2) ? s2 : s3;
      if (kq == 0) y_lds[rbase + 4] = s4;
    }
    __syncthreads();
    // 4. gates + state update (PyTorch GRUCell order r,z,n)
    if (t < HID) {
      const _Float16* gih = gi_lds[cur];
      const float ir = (float)gih[t];
      const float iz = (float)gih[200 + t];
      const float inn = (float)gih[400 + t];
      const float rgt = sigm(ir + y_lds[t] + bb0);
      const float zg = sigm(iz + y_lds[200 + t] + bb1);
      const float ng = tanhf_(inn + rgt * (y_lds[400 + t] + bb2));
      hreg = (1.0f - zg) * ng + zg * hreg;
      h_sh[t] = (_Float16)hreg;
      hs[(size_t)(b * SEQ + s) * 400 + dir * HID + t] = (__half)hreg;
    }
    // 5. land prefetched gi row
    if (do_pf) ((h4*)gi_lds[nxt])[t] = pf;
    __syncthreads();
  }
}

// ---------------- final linear: [16384,400] x [400,10] ---------------------
__global__ __launch_bounds__(256) void final_linear(
    const __half* __restrict__ hs, const float* __restrict__ lin_w,
    const float* __restrict__ lin_b, float* __restrict__ out) {
  __shared__ _Float16 hsl[64][400];
  __shared__ _Float16 lwl[10][400];
  const int t = threadIdx.x;
  const int m0 = blockIdx.x * 64;
  const ushort4* hp = (const ushort4*)(hs + (size_t)m0 * 400);
  for (int idx = t; idx < 64 * 100; idx += 256) {
    ushort4 v = hp[idx];
    const int row = idx / 100, c = idx - row * 100;
    *(ushort4*)&hsl[row][c * 4] = v;
  }
  for (int idx = t; idx < 10 * 400; idx += 256) {
    (&lwl[0][0])[idx] = (_Float16)lin_w[idx];
  }
  __syncthreads();
  for (int idx = t; idx < 640; idx += 256) {
    const int m = idx / 10, c = idx - (idx / 10) * 10;
    const h2* hr = (const h2*)hsl[m];
    const h2* wr = (const h2*)lwl[c];
    float acc = 0.0f;
#pragma unroll 8
    for (int kk = 0; kk < 200; ++kk) acc = fdot2f(hr[kk], wr[kk], acc);
    out[(size_t)(m0 + m) * 10 + c] = acc + lin_b[c];
  }
}

extern "C" void kernel_launch(void* const* d_in, const int* in_sizes, int n_in,
                              void* d_out, int out_size, void* d_ws, size_t ws_size,
                              hipStream_t stream) {
  const int*   text   = (const int*)d_in[0];
  const float* emb    = (const float*)d_in[1];
  const float* w_ih_f = (const float*)d_in[2];
  const float* w_hh_f = (const float*)d_in[3];
  const float* b_ih_f = (const float*)d_in[4];
  const float* b_hh_f = (const float*)d_in[5];
  const float* w_ih_b = (const float*)d_in[6];
  const float* w_hh_b = (const float*)d_in[7];
  const float* b_ih_b = (const float*)d_in[8];
  const float* b_hh_b = (const float*)d_in[9];
  const float* lin_w  = (const float*)d_in[10];
  const float* lin_b  = (const float*)d_in[11];
  const float* h0_f   = (const float*)d_in[12];
  const float* h0_b   = (const float*)d_in[13];
  float* out = (float*)d_out;

  char* ws = (char*)d_ws;
  _Float16* Wfrag    = (_Float16*)(ws);                 //   778,240 B
  float*    bias_cat = (float*)(ws + 778240);           //     4,864 B
  __half*   gi       = (__half*)(ws + 783360);          // 39,321,600 B (stride 1200)
  _Float16* Wrow     = (_Float16*)(ws + 40104960);      //   480,064 B (+pad)
  __half*   hs       = (__half*)(ws + 40585088);        // 13,107,200 B (end ~53.7MB)

  prep_kernel<<<dim3(1520), dim3(256), 0, stream>>>(
      w_ih_f, w_ih_b, b_ih_f, b_ih_b, w_hh_f, w_hh_b, Wfrag, bias_cat, Wrow);
  gi_gemm<<<dim3(MTOT / 128), dim3(512), 0, stream>>>(
      text, emb, Wfrag, bias_cat, gi);
  gru_rec<<<dim3(64), dim3(512), 0, stream>>>(
      Wrow, b_hh_f, b_hh_b, h0_f, h0_b, gi, hs);
  final_linear<<<dim3(MTOT / 64), dim3(256), 0, stream>>>(
      hs, lin_w, lin_b, out);
}